// Round 2
// baseline (18434.155 us; speedup 1.0000x reference)
//
#include <hip/hip_runtime.h>
#include <hip/hip_bf16.h>
#include <stdint.h>
#include <stddef.h>

// Problem constants
#define B_ 4096
#define S_ 64
#define D_ 512
#define DEPTH_ 4

// ---------------------------------------------------------------------------
// R12 design (delta vs R11):
//  * ff1_fused: [x += P1; LN2; U = relu(x_ln @ W1 + b1)] — kills all 4
//    ln_sum1 dispatches/step. TM=32/TN=256, grid (128,8)=1024 blocks.
//  * addln_gemm: [h=Xprev+fold(PSPL); head(t-1); x=emb+h; LN1_0; P1=y@Wc0]
//    — kills add_ln + g1 (one kernel instead of two). Same geometry as
//    lnfold_gemm (TM=32, TN=128, grid 512).
//  * g3: split-K 4 -> 2 with TN=64 (grid (32,8,2)=512): 16 BK-iters/block
//    (vs 8) for better fixed-cost amortization; PSPL halves to 8 MB.
//  * Y buffer gone — every LN output lives only in LDS now.
//  * X ping-pong XA/XB: 8 alternating writes/step, always ends on XB.
//  * Locked per R10/R11: m97 2-barrier K-loop, BK=64, global_load_lds
//    width=16, coalesced LDS-staged epilogues, grids >=512 blocks, no
//    cross-block sync, no XCD swizzle.
// ---------------------------------------------------------------------------

typedef __attribute__((ext_vector_type(8))) __bf16 bf16x8;
typedef __attribute__((ext_vector_type(4))) float f32x4;
typedef __hip_bfloat16 bf16_t;

constexpr int SPLITZ = 2;   // g3 split-K partials

__device__ __forceinline__ void async_copy16(const void* g, void* lds) {
  __builtin_amdgcn_global_load_lds(
      (const __attribute__((address_space(1))) void*)g,
      (__attribute__((address_space(3))) void*)lds, 16, 0, 0);
}

__device__ __forceinline__ float bf2f(bf16_t h) { return __bfloat162float(h); }

// fold bf16 partial row-chunk into v[8]
__device__ __forceinline__ void fold_p(float v[8], const bf16_t* pz)
{
  alignas(16) bf16_t t[8];
  *(uint4*)t = *(const uint4*)pz;
#pragma unroll
  for (int i = 0; i < 8; ++i) v[i] += bf2f(t[i]);
}

// LayerNorm row helper: v[8] per lane (64 lanes x 8 = 512), write bf16 row
// (yrow may be global or LDS — generic pointer)
__device__ __forceinline__ void ln_store(const float v[8],
                                         const float* __restrict__ gamma,
                                         const float* __restrict__ beta,
                                         bf16_t* yrow, int lane)
{
  float s = 0.f, ss = 0.f;
#pragma unroll
  for (int i = 0; i < 8; ++i) { s += v[i]; ss += v[i] * v[i]; }
#pragma unroll
  for (int o = 32; o; o >>= 1) { s += __shfl_xor(s, o); ss += __shfl_xor(ss, o); }
  const float m   = s * (1.f / D_);
  const float inv = rsqrtf(ss * (1.f / D_) - m * m + 1e-5f);
  const int c0 = lane * 8;
  float g[8], b[8];
  *(float4*)&g[0] = *(const float4*)&gamma[c0];
  *(float4*)&g[4] = *(const float4*)&gamma[c0 + 4];
  *(float4*)&b[0] = *(const float4*)&beta[c0];
  *(float4*)&b[4] = *(const float4*)&beta[c0 + 4];
  alignas(16) bf16_t o8[8];
#pragma unroll
  for (int i = 0; i < 8; ++i)
    o8[i] = __float2bfloat16((v[i] - m) * inv * g[i] + b[i]);
  *(uint4*)&yrow[c0] = *(const uint4*)o8;
}

// ---------------------------------------------------------------------------
// GEMM (used for g3 only now): C(M,N) = A(M,K) @ Bt(N,K)^T  (+bias)
//   EPI 2: O[z*M*N + row*N+col] = bf16(acc (+bias if z==0))
// ---------------------------------------------------------------------------
template<int TM, int TN, int EPI, int SPLITK>
__launch_bounds__(256)
__global__ void gemm_bf16(const bf16_t* __restrict__ A,
                          const bf16_t* __restrict__ Bt,
                          const float* __restrict__ bias,
                          bf16_t* __restrict__ O,
                          int M, int N, int K)
{
  constexpr int BK  = 64;
  constexpr int WM  = TM / 2, WN = TN / 2;
  constexpr int NMI = WM / 16, NNI = WN / 16;
  constexpr int CA  = TM / 8, CB = TN / 8;   // 1KB chunks (8 rows of 128B)
  static_assert(TM * TN <= (TM + TN) * BK, "C tile must fit in staging LDS");

  __shared__ __align__(16) bf16_t smem[(TM + TN) * BK];
  bf16_t* sA = smem;
  bf16_t* sB = smem + TM * BK;

  const int tid  = threadIdx.x;
  const int lane = tid & 63;
  const int wave = tid >> 6;
  const int wm   = wave & 1;
  const int wn   = wave >> 1;
  const int m0   = blockIdx.x * TM;
  const int n0   = blockIdx.y * TN;
  const int KS   = K / SPLITK;
  const int kbeg = blockIdx.z * KS;

  const int lr = lane >> 3;        // row within 1KB chunk (8 rows)
  const int lc = (lane & 7) * 8;   // bf16 col within row

  f32x4 acc[NMI][NNI];
#pragma unroll
  for (int mi = 0; mi < NMI; ++mi)
#pragma unroll
    for (int ni = 0; ni < NNI; ++ni)
      acc[mi][ni] = (f32x4){0.f, 0.f, 0.f, 0.f};

  for (int k0 = kbeg; k0 < kbeg + KS; k0 += BK) {
#pragma unroll
    for (int c = wave; c < CA; c += 4) {
      const bf16_t* g = A + (size_t)(m0 + c * 8 + lr) * K + (k0 + lc);
      async_copy16(g, (char*)sA + c * 1024);
    }
#pragma unroll
    for (int c = wave; c < CB; c += 4) {
      const bf16_t* g = Bt + (size_t)(n0 + c * 8 + lr) * K + (k0 + lc);
      async_copy16(g, (char*)sB + c * 1024);
    }
    __syncthreads();   // drains vmcnt(0) -> LDS ready

#pragma unroll
    for (int kk = 0; kk < BK; kk += 32) {
      bf16x8 af[NMI], bfv[NNI];
#pragma unroll
      for (int mi = 0; mi < NMI; ++mi)
        af[mi] = *(const bf16x8*)&sA[(wm * WM + mi * 16 + (lane & 15)) * BK + kk + (lane >> 4) * 8];
#pragma unroll
      for (int ni = 0; ni < NNI; ++ni)
        bfv[ni] = *(const bf16x8*)&sB[(wn * WN + ni * 16 + (lane & 15)) * BK + kk + (lane >> 4) * 8];
#pragma unroll
      for (int mi = 0; mi < NMI; ++mi)
#pragma unroll
        for (int ni = 0; ni < NNI; ++ni)
          acc[mi][ni] = __builtin_amdgcn_mfma_f32_16x16x32_bf16(af[mi], bfv[ni], acc[mi][ni], 0, 0, 0);
    }
    __syncthreads();   // protect LDS before next stage / before sC reuse
  }

  // Coalesced epilogue: round into LDS (reuse staging buffer), then
  // row-major uint4 stores. C/D layout (m89/m91): col=lane&15,
  // row=(lane>>4)*4 + r.
  bf16_t* sC = smem;
#pragma unroll
  for (int mi = 0; mi < NMI; ++mi) {
#pragma unroll
    for (int ni = 0; ni < NNI; ++ni) {
      const int col  = wn * WN + ni * 16 + (lane & 15);
      const int row0 = wm * WM + mi * 16 + ((lane >> 4) << 2);
      const float bv = (SPLITK == 1 || blockIdx.z == 0) ? bias[n0 + col] : 0.f;
#pragma unroll
      for (int r = 0; r < 4; ++r) {
        float v = acc[mi][ni][r] + bv;
        if constexpr (EPI == 1) v = v > 0.f ? v : 0.f;
        sC[(row0 + r) * TN + col] = __float2bfloat16(v);
      }
    }
  }
  __syncthreads();
  bf16_t* Ob = O + (EPI == 2 ? (size_t)blockIdx.z * M * N : (size_t)0);
#pragma unroll
  for (int p = 0; p < (TM * TN) / 2048; ++p) {
    const int chunk = p * 256 + tid;
    const int rr = chunk / (TN / 8);
    const int cc = (chunk % (TN / 8)) * 8;
    *(uint4*)&Ob[(size_t)(m0 + rr) * N + n0 + cc] = *(const uint4*)&sC[rr * TN + cc];
  }
}

// ---------------------------------------------------------------------------
// Fused [x = Xin + sum_{z<SPLITZ} PSPL; LN1; P1 = y@Wc + bc], layers 1..3.
// TM=32 rows, TN=128 cols, BK=64; grid (B/32, 4) = 512 blocks, 256 thr.
// LDS: sY 32KB (full LN'd A-panel) + sB 16KB = 48KB -> 3 blocks/CU.
// blockIdx.y==0 writes Xout (ping-pong buffer, no race with Xin reads).
// ---------------------------------------------------------------------------
__launch_bounds__(256)
__global__ void lnfold_gemm(const float* __restrict__ Xin,
                            const bf16_t* __restrict__ P,
                            float* __restrict__ Xout,
                            const float* __restrict__ gamma,
                            const float* __restrict__ beta,
                            const bf16_t* __restrict__ Bt,   // WCT layer slice
                            const float* __restrict__ bias,  // BC layer slice
                            bf16_t* __restrict__ O)          // P1
{
  constexpr int TM = 32, TN = 128, BK = 64;
  __shared__ __align__(16) bf16_t sY[TM * D_];   // 32KB
  __shared__ __align__(16) bf16_t sB[TN * BK];   // 16KB

  const int tid  = threadIdx.x;
  const int lane = tid & 63;
  const int wave = tid >> 6;
  const int m0   = blockIdx.x * TM;
  const int n0   = blockIdx.y * TN;
  const int c0   = lane * 8;

  // ---- prologue: fold partials + LN, 8 rows per wave ----
#pragma unroll
  for (int i = 0; i < 8; ++i) {
    const int row  = wave * 8 + i;
    const int grow = m0 + row;
    const float* xr = Xin + (size_t)grow * D_ + c0;
    float v[8];
    *(float4*)&v[0] = *(const float4*)&xr[0];
    *(float4*)&v[4] = *(const float4*)&xr[4];
#pragma unroll
    for (int z = 0; z < SPLITZ; ++z)
      fold_p(v, P + (size_t)z * B_ * D_ + (size_t)grow * D_ + c0);
    if (blockIdx.y == 0) {
      float* xo = Xout + (size_t)grow * D_ + c0;
      *(float4*)&xo[0] = *(const float4*)&v[0];
      *(float4*)&xo[4] = *(const float4*)&v[4];
    }
    ln_store(v, gamma, beta, &sY[row * D_], lane);
  }
  // first K-iter's __syncthreads covers sY visibility.

  f32x4 acc[2][2];
#pragma unroll
  for (int mi = 0; mi < 2; ++mi)
#pragma unroll
    for (int ni = 0; ni < 2; ++ni)
      acc[mi][ni] = (f32x4){0.f, 0.f, 0.f, 0.f};

  const int lr = lane >> 3;
  const int lc = (lane & 7) * 8;
  for (int k0 = 0; k0 < D_; k0 += BK) {
#pragma unroll
    for (int c = wave; c < TN / 8; c += 4) {   // 16 chunks, 4/wave
      const bf16_t* g = Bt + (size_t)(n0 + c * 8 + lr) * D_ + (k0 + lc);
      async_copy16(g, (char*)sB + c * 1024);
    }
    __syncthreads();
#pragma unroll
    for (int kk = 0; kk < BK; kk += 32) {
      bf16x8 af[2], bfv[2];
#pragma unroll
      for (int mi = 0; mi < 2; ++mi)
        af[mi] = *(const bf16x8*)&sY[(mi * 16 + (lane & 15)) * D_ + k0 + kk + (lane >> 4) * 8];
#pragma unroll
      for (int ni = 0; ni < 2; ++ni)
        bfv[ni] = *(const bf16x8*)&sB[(wave * 32 + ni * 16 + (lane & 15)) * BK + kk + (lane >> 4) * 8];
#pragma unroll
      for (int mi = 0; mi < 2; ++mi)
#pragma unroll
        for (int ni = 0; ni < 2; ++ni)
          acc[mi][ni] = __builtin_amdgcn_mfma_f32_16x16x32_bf16(af[mi], bfv[ni], acc[mi][ni], 0, 0, 0);
    }
    __syncthreads();
  }

  // coalesced epilogue through sY (done with it now)
  bf16_t* sC = sY;
#pragma unroll
  for (int mi = 0; mi < 2; ++mi) {
#pragma unroll
    for (int ni = 0; ni < 2; ++ni) {
      const int col  = wave * 32 + ni * 16 + (lane & 15);
      const int row0 = mi * 16 + ((lane >> 4) << 2);
      const float bv = bias[n0 + col];
#pragma unroll
      for (int r = 0; r < 4; ++r)
        sC[(row0 + r) * TN + col] = __float2bfloat16(acc[mi][ni][r] + bv);
    }
  }
  __syncthreads();
#pragma unroll
  for (int p = 0; p < (TM * TN) / 2048; ++p) {   // 2 passes
    const int chunk = p * 256 + tid;
    const int rr = chunk / (TN / 8);
    const int cc = (chunk % (TN / 8)) * 8;
    *(uint4*)&O[(size_t)(m0 + rr) * D_ + n0 + cc] = *(const uint4*)&sC[rr * TN + cc];
  }
}

// ---------------------------------------------------------------------------
// Fused step boundary + g1 (layer 0):
//  h = hsrc (+ fold PSPL if P); head(t-1) from h (if out, blockIdx.y==0);
//  x = emb_a + emb_b + h -> Xout (y==0); y = LN1_0(x) -> sY;
//  P1 = y @ Wc0 + bc0.
// Same geometry as lnfold_gemm: TM=32, TN=128, grid (B/32, 4) = 512.
// ---------------------------------------------------------------------------
__launch_bounds__(256)
__global__ void addln_gemm(const int* __restrict__ a_seq,
                           const int* __restrict__ b_seq,
                           const float* __restrict__ bit_emb,
                           const float* __restrict__ hsrc, int hstride,
                           const bf16_t* __restrict__ P,
                           float* __restrict__ Xout,
                           const float* __restrict__ gamma,
                           const float* __restrict__ beta,
                           const bf16_t* __restrict__ Bt,   // WCT layer 0
                           const float* __restrict__ bias,  // BC layer 0
                           bf16_t* __restrict__ O,          // P1
                           int t,
                           const float* __restrict__ hw,
                           const float* __restrict__ hb,
                           float* __restrict__ out)
{
  constexpr int TM = 32, TN = 128, BK = 64;
  __shared__ __align__(16) bf16_t sY[TM * D_];   // 32KB
  __shared__ __align__(16) bf16_t sB[TN * BK];   // 16KB

  const int tid  = threadIdx.x;
  const int lane = tid & 63;
  const int wave = tid >> 6;
  const int m0   = blockIdx.x * TM;
  const int n0   = blockIdx.y * TN;
  const int c0   = lane * 8;

  const bool do_head = (out != nullptr) && (blockIdx.y == 0);
  float w[16];
  if (do_head) {
#pragma unroll
    for (int i = 0; i < 4; ++i)
      *(float4*)&w[i * 4] = *(const float4*)&hw[lane * 16 + i * 4];
  }

#pragma unroll
  for (int i = 0; i < 8; ++i) {
    const int row  = wave * 8 + i;
    const int grow = m0 + row;
    const int ai = a_seq[grow * S_ + t];
    const int bi = b_seq[grow * S_ + t];
    const float* pr = hsrc + (size_t)grow * hstride + c0;
    float p[8];
    *(float4*)&p[0] = *(const float4*)&pr[0];
    *(float4*)&p[4] = *(const float4*)&pr[4];
    if (P != nullptr) {
#pragma unroll
      for (int z = 0; z < SPLITZ; ++z)
        fold_p(p, P + (size_t)z * B_ * D_ + (size_t)grow * D_ + c0);
    }
    if (do_head) {
      float s0 = 0.f, s1 = 0.f;
#pragma unroll
      for (int j = 0; j < 8; ++j) { s0 += p[j] * w[2 * j]; s1 += p[j] * w[2 * j + 1]; }
#pragma unroll
      for (int o = 32; o; o >>= 1) { s0 += __shfl_xor(s0, o); s1 += __shfl_xor(s1, o); }
      if (lane == 0) {
        float* po = out + (size_t)grow * (S_ * 2) + (t - 1) * 2;
        po[0] = s0 + hb[0];
        po[1] = s1 + hb[1];
      }
    }
    float ea[8], eb[8], v[8];
    *(float4*)&ea[0] = *(const float4*)&bit_emb[ai * D_ + c0];
    *(float4*)&ea[4] = *(const float4*)&bit_emb[ai * D_ + c0 + 4];
    *(float4*)&eb[0] = *(const float4*)&bit_emb[bi * D_ + c0];
    *(float4*)&eb[4] = *(const float4*)&bit_emb[bi * D_ + c0 + 4];
#pragma unroll
    for (int j = 0; j < 8; ++j) v[j] = ea[j] + eb[j] + p[j];
    if (blockIdx.y == 0) {
      float* xo = Xout + (size_t)grow * D_ + c0;
      *(float4*)&xo[0] = *(const float4*)&v[0];
      *(float4*)&xo[4] = *(const float4*)&v[4];
    }
    ln_store(v, gamma, beta, &sY[row * D_], lane);
  }

  f32x4 acc[2][2];
#pragma unroll
  for (int mi = 0; mi < 2; ++mi)
#pragma unroll
    for (int ni = 0; ni < 2; ++ni)
      acc[mi][ni] = (f32x4){0.f, 0.f, 0.f, 0.f};

  const int lr = lane >> 3;
  const int lc = (lane & 7) * 8;
  for (int k0 = 0; k0 < D_; k0 += BK) {
#pragma unroll
    for (int c = wave; c < TN / 8; c += 4) {
      const bf16_t* g = Bt + (size_t)(n0 + c * 8 + lr) * D_ + (k0 + lc);
      async_copy16(g, (char*)sB + c * 1024);
    }
    __syncthreads();
#pragma unroll
    for (int kk = 0; kk < BK; kk += 32) {
      bf16x8 af[2], bfv[2];
#pragma unroll
      for (int mi = 0; mi < 2; ++mi)
        af[mi] = *(const bf16x8*)&sY[(mi * 16 + (lane & 15)) * D_ + k0 + kk + (lane >> 4) * 8];
#pragma unroll
      for (int ni = 0; ni < 2; ++ni)
        bfv[ni] = *(const bf16x8*)&sB[(wave * 32 + ni * 16 + (lane & 15)) * BK + kk + (lane >> 4) * 8];
#pragma unroll
      for (int mi = 0; mi < 2; ++mi)
#pragma unroll
        for (int ni = 0; ni < 2; ++ni)
          acc[mi][ni] = __builtin_amdgcn_mfma_f32_16x16x32_bf16(af[mi], bfv[ni], acc[mi][ni], 0, 0, 0);
    }
    __syncthreads();
  }

  bf16_t* sC = sY;
#pragma unroll
  for (int mi = 0; mi < 2; ++mi) {
#pragma unroll
    for (int ni = 0; ni < 2; ++ni) {
      const int col  = wave * 32 + ni * 16 + (lane & 15);
      const int row0 = mi * 16 + ((lane >> 4) << 2);
      const float bv = bias[n0 + col];
#pragma unroll
      for (int r = 0; r < 4; ++r)
        sC[(row0 + r) * TN + col] = __float2bfloat16(acc[mi][ni][r] + bv);
    }
  }
  __syncthreads();
#pragma unroll
  for (int p = 0; p < (TM * TN) / 2048; ++p) {
    const int chunk = p * 256 + tid;
    const int rr = chunk / (TN / 8);
    const int cc = (chunk % (TN / 8)) * 8;
    *(uint4*)&O[(size_t)(m0 + rr) * D_ + n0 + cc] = *(const uint4*)&sC[rr * TN + cc];
  }
}

// ---------------------------------------------------------------------------
// Fused [x = Xin + P1; LN2; U = relu(y @ W1 + b1)], every layer.
// TM=32, TN=256, BK=64; grid (B/32, 8) = 1024 blocks, 256 thr.
// LDS: sY 32KB + sB 32KB = 64KB -> 2 blocks/CU.
// Wave split 1x4: all waves rows 0..31 (NMI=2), cols wave*64 (NNI=4).
// ---------------------------------------------------------------------------
__launch_bounds__(256)
__global__ void ff1_fused(const float* __restrict__ Xin,
                          const bf16_t* __restrict__ P1,
                          float* __restrict__ Xout,
                          const float* __restrict__ gamma,
                          const float* __restrict__ beta,
                          const bf16_t* __restrict__ Bt,   // FF1T layer slice
                          const float* __restrict__ bias,  // ff1_b layer slice
                          bf16_t* __restrict__ U)
{
  constexpr int TM = 32, TN = 256, BK = 64, NFF = 4 * D_;
  __shared__ __align__(16) bf16_t sY[TM * D_];   // 32KB
  __shared__ __align__(16) bf16_t sB[TN * BK];   // 32KB

  const int tid  = threadIdx.x;
  const int lane = tid & 63;
  const int wave = tid >> 6;
  const int m0   = blockIdx.x * TM;
  const int n0   = blockIdx.y * TN;
  const int c0   = lane * 8;

  // ---- prologue: x = Xin + P1 ; write Xout (y==0) ; sY = LN2(x) ----
#pragma unroll
  for (int i = 0; i < 8; ++i) {
    const int row  = wave * 8 + i;
    const int grow = m0 + row;
    const float* xr = Xin + (size_t)grow * D_ + c0;
    float v[8];
    *(float4*)&v[0] = *(const float4*)&xr[0];
    *(float4*)&v[4] = *(const float4*)&xr[4];
    fold_p(v, P1 + (size_t)grow * D_ + c0);
    if (blockIdx.y == 0) {
      float* xo = Xout + (size_t)grow * D_ + c0;
      *(float4*)&xo[0] = *(const float4*)&v[0];
      *(float4*)&xo[4] = *(const float4*)&v[4];
    }
    ln_store(v, gamma, beta, &sY[row * D_], lane);
  }

  f32x4 acc[2][4];
#pragma unroll
  for (int mi = 0; mi < 2; ++mi)
#pragma unroll
    for (int ni = 0; ni < 4; ++ni)
      acc[mi][ni] = (f32x4){0.f, 0.f, 0.f, 0.f};

  const int lr = lane >> 3;
  const int lc = (lane & 7) * 8;
  for (int k0 = 0; k0 < D_; k0 += BK) {
#pragma unroll
    for (int c = wave; c < TN / 8; c += 4) {   // 32 chunks, 8/wave
      const bf16_t* g = Bt + (size_t)(n0 + c * 8 + lr) * D_ + (k0 + lc);
      async_copy16(g, (char*)sB + c * 1024);
    }
    __syncthreads();
#pragma unroll
    for (int kk = 0; kk < BK; kk += 32) {
      bf16x8 af[2], bfv[4];
#pragma unroll
      for (int mi = 0; mi < 2; ++mi)
        af[mi] = *(const bf16x8*)&sY[(mi * 16 + (lane & 15)) * D_ + k0 + kk + (lane >> 4) * 8];
#pragma unroll
      for (int ni = 0; ni < 4; ++ni)
        bfv[ni] = *(const bf16x8*)&sB[(wave * 64 + ni * 16 + (lane & 15)) * BK + kk + (lane >> 4) * 8];
#pragma unroll
      for (int mi = 0; mi < 2; ++mi)
#pragma unroll
        for (int ni = 0; ni < 4; ++ni)
          acc[mi][ni] = __builtin_amdgcn_mfma_f32_16x16x32_bf16(af[mi], bfv[ni], acc[mi][ni], 0, 0, 0);
    }
    __syncthreads();
  }

  // relu+bias epilogue through sY (16KB needed, have 32KB)
  bf16_t* sC = sY;
#pragma unroll
  for (int mi = 0; mi < 2; ++mi) {
#pragma unroll
    for (int ni = 0; ni < 4; ++ni) {
      const int col  = wave * 64 + ni * 16 + (lane & 15);
      const int row0 = mi * 16 + ((lane >> 4) << 2);
      const float bv = bias[n0 + col];
#pragma unroll
      for (int r = 0; r < 4; ++r) {
        float v = acc[mi][ni][r] + bv;
        sC[(row0 + r) * TN + col] = __float2bfloat16(v > 0.f ? v : 0.f);
      }
    }
  }
  __syncthreads();
#pragma unroll
  for (int p = 0; p < (TM * TN) / 2048; ++p) {   // 4 passes
    const int chunk = p * 256 + tid;
    const int rr = chunk >> 5;          // TN/8 = 32
    const int cc = (chunk & 31) * 8;
    *(uint4*)&U[(size_t)(m0 + rr) * NFF + n0 + cc] = *(const uint4*)&sC[rr * TN + cc];
  }
}

// Final head: h = X + P0..P1; logits[row, S-1, :] = h @ head_w + head_b.
__global__ void head_kernel(const float* __restrict__ X,
                            const bf16_t* __restrict__ P,
                            const float* __restrict__ hw,
                            const float* __restrict__ hb,
                            float* __restrict__ out, int t)
{
  const int row  = blockIdx.x * 4 + (threadIdx.x >> 6);
  const int lane = threadIdx.x & 63;
  const float* xr = X + (size_t)row * D_;
  const int c0 = lane * 8;
  float v[8];
  *(float4*)&v[0] = *(const float4*)&xr[c0];
  *(float4*)&v[4] = *(const float4*)&xr[c0 + 4];
#pragma unroll
  for (int z = 0; z < SPLITZ; ++z)
    fold_p(v, P + (size_t)z * B_ * D_ + (size_t)row * D_ + c0);
  float w[16];
#pragma unroll
  for (int i = 0; i < 4; ++i)
    *(float4*)&w[i * 4] = *(const float4*)&hw[lane * 16 + i * 4];
  float s0 = 0.f, s1 = 0.f;
#pragma unroll
  for (int i = 0; i < 8; ++i) { s0 += v[i] * w[2 * i]; s1 += v[i] * w[2 * i + 1]; }
#pragma unroll
  for (int o = 32; o; o >>= 1) { s0 += __shfl_xor(s0, o); s1 += __shfl_xor(s1, o); }
  if (lane == 0) {
    float* po = out + (size_t)row * (S_ * 2) + t * 2;
    po[0] = s0 + hb[0];
    po[1] = s1 + hb[1];
  }
}

// ---------------------------------------------------------------------------
// Prep kernels (run every launch; graph-safe)
// ---------------------------------------------------------------------------
__global__ void prep_wc(const float* __restrict__ qkv_w,
                        const float* __restrict__ out_w,
                        float* __restrict__ wc)
{
  const int n = blockIdx.x * 256 + threadIdx.x;
  const int k = blockIdx.y;
  const int l = blockIdx.z;
  const float* qrow = qkv_w + ((size_t)l * D_ + k) * (3 * D_) + 2 * D_;
  const float* ow   = out_w + (size_t)l * D_ * D_;
  float acc = 0.f;
  for (int j = 0; j < D_; ++j) acc += qrow[j] * ow[(size_t)j * D_ + n];
  wc[((size_t)l * D_ + k) * D_ + n] = acc;
}

__global__ void prep_bc(const float* __restrict__ qkv_b,
                        const float* __restrict__ out_w,
                        const float* __restrict__ out_b,
                        float* __restrict__ bc)
{
  const int l = blockIdx.x;
  const int n = threadIdx.x;
  const float* qb = qkv_b + (size_t)l * (3 * D_) + 2 * D_;
  const float* ow = out_w + (size_t)l * D_ * D_;
  float acc = out_b[(size_t)l * D_ + n];
  for (int j = 0; j < D_; ++j) acc += qb[j] * ow[(size_t)j * D_ + n];
  bc[(size_t)l * D_ + n] = acc;
}

// dst(C,R) bf16 = transpose(src(R,C) fp32), per-layer via blockIdx.z
__global__ void transpose_conv(const float* __restrict__ src,
                               bf16_t* __restrict__ dst, int R, int C)
{
  __shared__ float tile[32][33];
  const int l = blockIdx.z;
  const float* s = src + (size_t)l * R * C;
  bf16_t* d = dst + (size_t)l * R * C;
  const int c0 = blockIdx.x * 32, r0 = blockIdx.y * 32;
  const int tx = threadIdx.x, ty = threadIdx.y;
  tile[ty][tx] = s[(size_t)(r0 + ty) * C + (c0 + tx)];
  __syncthreads();
  d[(size_t)(c0 + ty) * R + (r0 + tx)] = __float2bfloat16(tile[tx][ty]);
}

// ---------------------------------------------------------------------------
extern "C" void kernel_launch(void* const* d_in, const int* in_sizes, int n_in,
                              void* d_out, int out_size, void* d_ws, size_t ws_size,
                              hipStream_t stream)
{
  const int*   a_seq     = (const int*)  d_in[0];
  const int*   b_seq     = (const int*)  d_in[1];
  const float* bit_emb   = (const float*)d_in[2];
  const float* start     = (const float*)d_in[3];
  const float* ln1_g     = (const float*)d_in[4];
  const float* ln1_b     = (const float*)d_in[5];
  const float* qkv_w     = (const float*)d_in[6];
  const float* qkv_b     = (const float*)d_in[7];
  const float* out_w     = (const float*)d_in[8];
  const float* out_b     = (const float*)d_in[9];
  const float* ln2_g     = (const float*)d_in[10];
  const float* ln2_b     = (const float*)d_in[11];
  const float* ff1_w     = (const float*)d_in[12];
  const float* ff1_b     = (const float*)d_in[13];
  const float* ff2_w     = (const float*)d_in[14];
  const float* ff2_b     = (const float*)d_in[15];
  const float* head_w    = (const float*)d_in[16];
  const float* head_b    = (const float*)d_in[17];
  float* out = (float*)d_out;

  // workspace layout
  char* ws = (char*)d_ws;
  float*  XA    = (float*) ws; ws += (size_t)B_ * D_ * 4;              // 8 MB
  float*  XB    = (float*) ws; ws += (size_t)B_ * D_ * 4;              // 8 MB
  bf16_t* U     = (bf16_t*)ws; ws += (size_t)B_ * 4 * D_ * 2;          // 16 MB
  bf16_t* WCT   = (bf16_t*)ws; ws += (size_t)DEPTH_ * D_ * D_ * 2;     // 2 MB
  bf16_t* FF1T  = (bf16_t*)ws; ws += (size_t)DEPTH_ * D_ * 4 * D_ * 2; // 8 MB
  bf16_t* FF2T  = (bf16_t*)ws; ws += (size_t)DEPTH_ * 4 * D_ * D_ * 2; // 8 MB
  float*  BC    = (float*) ws; ws += (size_t)DEPTH_ * D_ * 4;          // 8 KB
  float*  WCTMP = (float*) ws; ws += (size_t)DEPTH_ * D_ * D_ * 4;     // 4 MB
  bf16_t* PSPL  = (bf16_t*)ws; ws += (size_t)SPLITZ * B_ * D_ * 2;     // 8 MB g3 split-K partials
  bf16_t* P1    = (bf16_t*)ws; ws += (size_t)B_ * D_ * 2;              // 4 MB g1 partial

  // ---- weight prep (per launch, identical every call) ----
  prep_wc<<<dim3(2, 512, 4), 256, 0, stream>>>(qkv_w, out_w, WCTMP);
  prep_bc<<<4, 512, 0, stream>>>(qkv_b, out_w, out_b, BC);
  transpose_conv<<<dim3(16, 16, 4),  dim3(32, 32), 0, stream>>>(WCTMP, WCT, 512, 512);
  transpose_conv<<<dim3(64, 16, 4),  dim3(32, 32), 0, stream>>>(ff1_w, FF1T, 512, 2048);
  transpose_conv<<<dim3(16, 64, 4),  dim3(32, 32), 0, stream>>>(ff2_w, FF2T, 2048, 512);

  // ---- recurrent steps ----
  // X ping-pong: addln XB->XA, then 8 alternating writes (ff1/lnfold),
  // ending every step on XB. Stream order serializes all read/write pairs;
  // no kernel reads and writes the same X buffer.
  for (int t = 0; t < S_; ++t) {
    if (t == 0)
      addln_gemm<<<dim3(B_ / 32, 4), 256, 0, stream>>>(
          a_seq, b_seq, bit_emb, start, 0, nullptr, XA,
          ln1_g, ln1_b, WCT, BC, P1, t, head_w, head_b, nullptr);
    else
      addln_gemm<<<dim3(B_ / 32, 4), 256, 0, stream>>>(
          a_seq, b_seq, bit_emb, XB, D_, PSPL, XA,
          ln1_g, ln1_b, WCT, BC, P1, t, head_w, head_b, out);
    float* cur = XA;
    float* alt = XB;
    for (int l = 0; l < DEPTH_; ++l) {
      if (l > 0) {
        // x = cur + fold(PSPL) -> alt ; y = LN1[l](x) ; P1 = y@Wc[l]+bc[l]
        lnfold_gemm<<<dim3(B_ / 32, 4), 256, 0, stream>>>(
            cur, PSPL, alt,
            ln1_g + (size_t)l * D_, ln1_b + (size_t)l * D_,
            WCT + (size_t)l * D_ * D_, BC + (size_t)l * D_, P1);
        float* tmp = cur; cur = alt; alt = tmp;
      }
      // x = cur + P1 -> alt ; y = LN2[l](x) ; U = relu(y @ ff1[l] + b1)
      ff1_fused<<<dim3(B_ / 32, 8), 256, 0, stream>>>(
          cur, P1, alt,
          ln2_g + (size_t)l * D_, ln2_b + (size_t)l * D_,
          FF1T + (size_t)l * D_ * 4 * D_, ff1_b + (size_t)l * 4 * D_, U);
      { float* tmp = cur; cur = alt; alt = tmp; }
      // PSPL[z] = bf16(u @ ff2[l] (+b2 in z=0)) — split-K=2, TN=64,
      // grid (32,8,2)=512 blocks, 16 BK-iters/block
      gemm_bf16<128, 64, 2, SPLITZ><<<dim3(32, 8, SPLITZ), 256, 0, stream>>>(
          U, FF2T + (size_t)l * 4 * D_ * D_, ff2_b + (size_t)l * D_, PSPL,
          B_, D_, 4 * D_);
      // partials folded by next lnfold / addln / head
    }
    // loop invariant: cur == XB here (8 swaps/step)
  }
  head_kernel<<<B_ / 4, 256, 0, stream>>>(XB, PSPL, head_w, head_b, out, S_ - 1);
}

// Round 3
// 14889.468 us; speedup vs baseline: 1.2381x; 1.2381x over previous
//
#include <hip/hip_runtime.h>
#include <hip/hip_bf16.h>
#include <stdint.h>
#include <stddef.h>

// Problem constants
#define B_ 4096
#define S_ 64
#define D_ 512
#define DEPTH_ 4

// ---------------------------------------------------------------------------
// R13 design = R11 (best known, 14907us) + exactly one delta:
//  * addln_gemm replaces add_ln + g1: [h=Xprev+fold(PSPL); head(t-1);
//    x=emb+h -> XA; y=LN1_0(x) -> LDS; P1=y@Wc0+bc0]. Same TM=32/TN=128
//    geometry as the validated lnfold_gemm; layer-0 GEMM bit-identical
//    (same K order). Kills 1 dispatch/step + the 8MB Y round-trip for l=0,
//    and upgrades g1's staging intensity 16 -> 25.6 MAC/byte.
//  * REVERTED from R12 (post-mortem: ff1_fused's TM=32 halved the big
//    GEMM's staging intensity, +3.5ms): g2 is 128x128 + separate ln_sum1;
//    g3 is 128x128 split-K=4; SPLITZ=4 partials everywhere.
//  * Locked per R10/R11: m97 2-barrier K-loop, BK=64, global_load_lds
//    width=16, coalesced LDS-staged epilogues, grids >=512 blocks, no
//    cross-block sync, no XCD swizzle.
// ---------------------------------------------------------------------------

typedef __attribute__((ext_vector_type(8))) __bf16 bf16x8;
typedef __attribute__((ext_vector_type(4))) float f32x4;
typedef __hip_bfloat16 bf16_t;

constexpr int SPLITZ = 4;   // g3 split-K partials

__device__ __forceinline__ void async_copy16(const void* g, void* lds) {
  __builtin_amdgcn_global_load_lds(
      (const __attribute__((address_space(1))) void*)g,
      (__attribute__((address_space(3))) void*)lds, 16, 0, 0);
}

__device__ __forceinline__ float bf2f(bf16_t h) { return __bfloat162float(h); }

// fold bf16 partial row-chunk into v[8]
__device__ __forceinline__ void fold_p(float v[8], const bf16_t* pz)
{
  alignas(16) bf16_t t[8];
  *(uint4*)t = *(const uint4*)pz;
#pragma unroll
  for (int i = 0; i < 8; ++i) v[i] += bf2f(t[i]);
}

// LayerNorm row helper: v[8] per lane (64 lanes x 8 = 512), write bf16 row
// (yrow may be global or LDS — generic pointer)
__device__ __forceinline__ void ln_store(const float v[8],
                                         const float* __restrict__ gamma,
                                         const float* __restrict__ beta,
                                         bf16_t* yrow, int lane)
{
  float s = 0.f, ss = 0.f;
#pragma unroll
  for (int i = 0; i < 8; ++i) { s += v[i]; ss += v[i] * v[i]; }
#pragma unroll
  for (int o = 32; o; o >>= 1) { s += __shfl_xor(s, o); ss += __shfl_xor(ss, o); }
  const float m   = s * (1.f / D_);
  const float inv = rsqrtf(ss * (1.f / D_) - m * m + 1e-5f);
  const int c0 = lane * 8;
  float g[8], b[8];
  *(float4*)&g[0] = *(const float4*)&gamma[c0];
  *(float4*)&g[4] = *(const float4*)&gamma[c0 + 4];
  *(float4*)&b[0] = *(const float4*)&beta[c0];
  *(float4*)&b[4] = *(const float4*)&beta[c0 + 4];
  alignas(16) bf16_t o8[8];
#pragma unroll
  for (int i = 0; i < 8; ++i)
    o8[i] = __float2bfloat16((v[i] - m) * inv * g[i] + b[i]);
  *(uint4*)&yrow[c0] = *(const uint4*)o8;
}

// ---------------------------------------------------------------------------
// GEMM: C(M,N) = A(M,K) @ Bt(N,K)^T  (+bias)
//   EPI 1: O[row*N+col]  = bf16(relu(acc+b))   (SPLITK==1)
//   EPI 2: O[z*M*N + row*N+col] = bf16(acc (+bias if z==0))
// ---------------------------------------------------------------------------
template<int TM, int TN, int EPI, int SPLITK>
__launch_bounds__(256)
__global__ void gemm_bf16(const bf16_t* __restrict__ A,
                          const bf16_t* __restrict__ Bt,
                          const float* __restrict__ bias,
                          bf16_t* __restrict__ O,
                          int M, int N, int K)
{
  constexpr int BK  = 64;
  constexpr int WM  = TM / 2, WN = TN / 2;
  constexpr int NMI = WM / 16, NNI = WN / 16;
  constexpr int CA  = TM / 8, CB = TN / 8;   // 1KB chunks (8 rows of 128B)
  static_assert(TM * TN <= (TM + TN) * BK, "C tile must fit in staging LDS");

  __shared__ __align__(16) bf16_t smem[(TM + TN) * BK];
  bf16_t* sA = smem;
  bf16_t* sB = smem + TM * BK;

  const int tid  = threadIdx.x;
  const int lane = tid & 63;
  const int wave = tid >> 6;
  const int wm   = wave & 1;
  const int wn   = wave >> 1;
  const int m0   = blockIdx.x * TM;
  const int n0   = blockIdx.y * TN;
  const int KS   = K / SPLITK;
  const int kbeg = blockIdx.z * KS;

  const int lr = lane >> 3;        // row within 1KB chunk (8 rows)
  const int lc = (lane & 7) * 8;   // bf16 col within row

  f32x4 acc[NMI][NNI];
#pragma unroll
  for (int mi = 0; mi < NMI; ++mi)
#pragma unroll
    for (int ni = 0; ni < NNI; ++ni)
      acc[mi][ni] = (f32x4){0.f, 0.f, 0.f, 0.f};

  for (int k0 = kbeg; k0 < kbeg + KS; k0 += BK) {
#pragma unroll
    for (int c = wave; c < CA; c += 4) {
      const bf16_t* g = A + (size_t)(m0 + c * 8 + lr) * K + (k0 + lc);
      async_copy16(g, (char*)sA + c * 1024);
    }
#pragma unroll
    for (int c = wave; c < CB; c += 4) {
      const bf16_t* g = Bt + (size_t)(n0 + c * 8 + lr) * K + (k0 + lc);
      async_copy16(g, (char*)sB + c * 1024);
    }
    __syncthreads();   // drains vmcnt(0) -> LDS ready

#pragma unroll
    for (int kk = 0; kk < BK; kk += 32) {
      bf16x8 af[NMI], bfv[NNI];
#pragma unroll
      for (int mi = 0; mi < NMI; ++mi)
        af[mi] = *(const bf16x8*)&sA[(wm * WM + mi * 16 + (lane & 15)) * BK + kk + (lane >> 4) * 8];
#pragma unroll
      for (int ni = 0; ni < NNI; ++ni)
        bfv[ni] = *(const bf16x8*)&sB[(wn * WN + ni * 16 + (lane & 15)) * BK + kk + (lane >> 4) * 8];
#pragma unroll
      for (int mi = 0; mi < NMI; ++mi)
#pragma unroll
        for (int ni = 0; ni < NNI; ++ni)
          acc[mi][ni] = __builtin_amdgcn_mfma_f32_16x16x32_bf16(af[mi], bfv[ni], acc[mi][ni], 0, 0, 0);
    }
    __syncthreads();   // protect LDS before next stage / before sC reuse
  }

  // Coalesced epilogue: round into LDS (reuse staging buffer), then
  // row-major uint4 stores. C/D layout (m89/m91): col=lane&15,
  // row=(lane>>4)*4 + r.
  bf16_t* sC = smem;
#pragma unroll
  for (int mi = 0; mi < NMI; ++mi) {
#pragma unroll
    for (int ni = 0; ni < NNI; ++ni) {
      const int col  = wn * WN + ni * 16 + (lane & 15);
      const int row0 = wm * WM + mi * 16 + ((lane >> 4) << 2);
      const float bv = (SPLITK == 1 || blockIdx.z == 0) ? bias[n0 + col] : 0.f;
#pragma unroll
      for (int r = 0; r < 4; ++r) {
        float v = acc[mi][ni][r] + bv;
        if constexpr (EPI == 1) v = v > 0.f ? v : 0.f;
        sC[(row0 + r) * TN + col] = __float2bfloat16(v);
      }
    }
  }
  __syncthreads();
  bf16_t* Ob = O + (EPI == 2 ? (size_t)blockIdx.z * M * N : (size_t)0);
#pragma unroll
  for (int p = 0; p < (TM * TN) / 2048; ++p) {
    const int chunk = p * 256 + tid;
    const int rr = chunk / (TN / 8);
    const int cc = (chunk % (TN / 8)) * 8;
    *(uint4*)&Ob[(size_t)(m0 + rr) * N + n0 + cc] = *(const uint4*)&sC[rr * TN + cc];
  }
}

// x = X + P1 (bf16 partial); write X; y = LN(x). 4 rows/block.
__global__ void ln_sum1_kernel(float* __restrict__ X,
                               const bf16_t* __restrict__ P,
                               const float* __restrict__ gamma,
                               const float* __restrict__ beta,
                               bf16_t* __restrict__ Y)
{
  const int row  = blockIdx.x * 4 + (threadIdx.x >> 6);
  const int lane = threadIdx.x & 63;
  const int c0 = lane * 8;
  float* xr = X + (size_t)row * D_;
  float v[8];
  *(float4*)&v[0] = *(const float4*)&xr[c0];
  *(float4*)&v[4] = *(const float4*)&xr[c0 + 4];
  fold_p(v, P + (size_t)row * D_ + c0);
  *(float4*)&xr[c0]     = *(const float4*)&v[0];
  *(float4*)&xr[c0 + 4] = *(const float4*)&v[4];
  ln_store(v, gamma, beta, Y + (size_t)row * D_, lane);
}

// ---------------------------------------------------------------------------
// Fused [x = Xin + sum_{z<4} PSPL; LN1; P1 = y@Wc + bc], layers 1..3.
// TM=32 rows, TN=128 cols, BK=64; grid (B/32, 4) = 512 blocks, 256 thr.
// LDS: sY 32KB (full LN'd A-panel) + sB 16KB = 48KB -> 3 blocks/CU.
// blockIdx.y==0 writes Xout (ping-pong buffer, no race with Xin reads).
// ---------------------------------------------------------------------------
__launch_bounds__(256)
__global__ void lnfold_gemm(const float* __restrict__ Xin,
                            const bf16_t* __restrict__ P,
                            float* __restrict__ Xout,
                            const float* __restrict__ gamma,
                            const float* __restrict__ beta,
                            const bf16_t* __restrict__ Bt,   // WCT layer slice
                            const float* __restrict__ bias,  // BC layer slice
                            bf16_t* __restrict__ O)          // P1
{
  constexpr int TM = 32, TN = 128, BK = 64;
  __shared__ __align__(16) bf16_t sY[TM * D_];   // 32KB
  __shared__ __align__(16) bf16_t sB[TN * BK];   // 16KB

  const int tid  = threadIdx.x;
  const int lane = tid & 63;
  const int wave = tid >> 6;
  const int m0   = blockIdx.x * TM;
  const int n0   = blockIdx.y * TN;
  const int c0   = lane * 8;

  // ---- prologue: fold partials + LN, 8 rows per wave ----
#pragma unroll
  for (int i = 0; i < 8; ++i) {
    const int row  = wave * 8 + i;
    const int grow = m0 + row;
    const float* xr = Xin + (size_t)grow * D_ + c0;
    float v[8];
    *(float4*)&v[0] = *(const float4*)&xr[0];
    *(float4*)&v[4] = *(const float4*)&xr[4];
#pragma unroll
    for (int z = 0; z < SPLITZ; ++z)
      fold_p(v, P + (size_t)z * B_ * D_ + (size_t)grow * D_ + c0);
    if (blockIdx.y == 0) {
      float* xo = Xout + (size_t)grow * D_ + c0;
      *(float4*)&xo[0] = *(const float4*)&v[0];
      *(float4*)&xo[4] = *(const float4*)&v[4];
    }
    ln_store(v, gamma, beta, &sY[row * D_], lane);
  }
  // first K-iter's __syncthreads covers sY visibility.

  f32x4 acc[2][2];
#pragma unroll
  for (int mi = 0; mi < 2; ++mi)
#pragma unroll
    for (int ni = 0; ni < 2; ++ni)
      acc[mi][ni] = (f32x4){0.f, 0.f, 0.f, 0.f};

  const int lr = lane >> 3;
  const int lc = (lane & 7) * 8;
  for (int k0 = 0; k0 < D_; k0 += BK) {
#pragma unroll
    for (int c = wave; c < TN / 8; c += 4) {   // 16 chunks, 4/wave
      const bf16_t* g = Bt + (size_t)(n0 + c * 8 + lr) * D_ + (k0 + lc);
      async_copy16(g, (char*)sB + c * 1024);
    }
    __syncthreads();
#pragma unroll
    for (int kk = 0; kk < BK; kk += 32) {
      bf16x8 af[2], bfv[2];
#pragma unroll
      for (int mi = 0; mi < 2; ++mi)
        af[mi] = *(const bf16x8*)&sY[(mi * 16 + (lane & 15)) * D_ + k0 + kk + (lane >> 4) * 8];
#pragma unroll
      for (int ni = 0; ni < 2; ++ni)
        bfv[ni] = *(const bf16x8*)&sB[(wave * 32 + ni * 16 + (lane & 15)) * BK + kk + (lane >> 4) * 8];
#pragma unroll
      for (int mi = 0; mi < 2; ++mi)
#pragma unroll
        for (int ni = 0; ni < 2; ++ni)
          acc[mi][ni] = __builtin_amdgcn_mfma_f32_16x16x32_bf16(af[mi], bfv[ni], acc[mi][ni], 0, 0, 0);
    }
    __syncthreads();
  }

  // coalesced epilogue through sY (done with it now)
  bf16_t* sC = sY;
#pragma unroll
  for (int mi = 0; mi < 2; ++mi) {
#pragma unroll
    for (int ni = 0; ni < 2; ++ni) {
      const int col  = wave * 32 + ni * 16 + (lane & 15);
      const int row0 = mi * 16 + ((lane >> 4) << 2);
      const float bv = bias[n0 + col];
#pragma unroll
      for (int r = 0; r < 4; ++r)
        sC[(row0 + r) * TN + col] = __float2bfloat16(acc[mi][ni][r] + bv);
    }
  }
  __syncthreads();
#pragma unroll
  for (int p = 0; p < (TM * TN) / 2048; ++p) {   // 2 passes
    const int chunk = p * 256 + tid;
    const int rr = chunk / (TN / 8);
    const int cc = (chunk % (TN / 8)) * 8;
    *(uint4*)&O[(size_t)(m0 + rr) * D_ + n0 + cc] = *(const uint4*)&sC[rr * TN + cc];
  }
}

// ---------------------------------------------------------------------------
// Fused step boundary + g1 (layer 0):
//  h = hsrc (+ fold PSPL if P); head(t-1) from h (if out, blockIdx.y==0);
//  x = emb_a + emb_b + h -> Xout (y==0); y = LN1_0(x) -> sY;
//  P1 = y @ Wc0 + bc0.
// Same geometry as lnfold_gemm: TM=32, TN=128, grid (B/32, 4) = 512.
// ---------------------------------------------------------------------------
__launch_bounds__(256)
__global__ void addln_gemm(const int* __restrict__ a_seq,
                           const int* __restrict__ b_seq,
                           const float* __restrict__ bit_emb,
                           const float* __restrict__ hsrc, int hstride,
                           const bf16_t* __restrict__ P,
                           float* __restrict__ Xout,
                           const float* __restrict__ gamma,
                           const float* __restrict__ beta,
                           const bf16_t* __restrict__ Bt,   // WCT layer 0
                           const float* __restrict__ bias,  // BC layer 0
                           bf16_t* __restrict__ O,          // P1
                           int t,
                           const float* __restrict__ hw,
                           const float* __restrict__ hb,
                           float* __restrict__ out)
{
  constexpr int TM = 32, TN = 128, BK = 64;
  __shared__ __align__(16) bf16_t sY[TM * D_];   // 32KB
  __shared__ __align__(16) bf16_t sB[TN * BK];   // 16KB

  const int tid  = threadIdx.x;
  const int lane = tid & 63;
  const int wave = tid >> 6;
  const int m0   = blockIdx.x * TM;
  const int n0   = blockIdx.y * TN;
  const int c0   = lane * 8;

  const bool do_head = (out != nullptr) && (blockIdx.y == 0);
  float w[16];
  if (do_head) {
#pragma unroll
    for (int i = 0; i < 4; ++i)
      *(float4*)&w[i * 4] = *(const float4*)&hw[lane * 16 + i * 4];
  }

#pragma unroll
  for (int i = 0; i < 8; ++i) {
    const int row  = wave * 8 + i;
    const int grow = m0 + row;
    const int ai = a_seq[grow * S_ + t];
    const int bi = b_seq[grow * S_ + t];
    const float* pr = hsrc + (size_t)grow * hstride + c0;
    float p[8];
    *(float4*)&p[0] = *(const float4*)&pr[0];
    *(float4*)&p[4] = *(const float4*)&pr[4];
    if (P != nullptr) {
#pragma unroll
      for (int z = 0; z < SPLITZ; ++z)
        fold_p(p, P + (size_t)z * B_ * D_ + (size_t)grow * D_ + c0);
    }
    if (do_head) {
      float s0 = 0.f, s1 = 0.f;
#pragma unroll
      for (int j = 0; j < 8; ++j) { s0 += p[j] * w[2 * j]; s1 += p[j] * w[2 * j + 1]; }
#pragma unroll
      for (int o = 32; o; o >>= 1) { s0 += __shfl_xor(s0, o); s1 += __shfl_xor(s1, o); }
      if (lane == 0) {
        float* po = out + (size_t)grow * (S_ * 2) + (t - 1) * 2;
        po[0] = s0 + hb[0];
        po[1] = s1 + hb[1];
      }
    }
    float ea[8], eb[8], v[8];
    *(float4*)&ea[0] = *(const float4*)&bit_emb[ai * D_ + c0];
    *(float4*)&ea[4] = *(const float4*)&bit_emb[ai * D_ + c0 + 4];
    *(float4*)&eb[0] = *(const float4*)&bit_emb[bi * D_ + c0];
    *(float4*)&eb[4] = *(const float4*)&bit_emb[bi * D_ + c0 + 4];
#pragma unroll
    for (int j = 0; j < 8; ++j) v[j] = ea[j] + eb[j] + p[j];
    if (blockIdx.y == 0) {
      float* xo = Xout + (size_t)grow * D_ + c0;
      *(float4*)&xo[0] = *(const float4*)&v[0];
      *(float4*)&xo[4] = *(const float4*)&v[4];
    }
    ln_store(v, gamma, beta, &sY[row * D_], lane);
  }

  f32x4 acc[2][2];
#pragma unroll
  for (int mi = 0; mi < 2; ++mi)
#pragma unroll
    for (int ni = 0; ni < 2; ++ni)
      acc[mi][ni] = (f32x4){0.f, 0.f, 0.f, 0.f};

  const int lr = lane >> 3;
  const int lc = (lane & 7) * 8;
  for (int k0 = 0; k0 < D_; k0 += BK) {
#pragma unroll
    for (int c = wave; c < TN / 8; c += 4) {
      const bf16_t* g = Bt + (size_t)(n0 + c * 8 + lr) * D_ + (k0 + lc);
      async_copy16(g, (char*)sB + c * 1024);
    }
    __syncthreads();
#pragma unroll
    for (int kk = 0; kk < BK; kk += 32) {
      bf16x8 af[2], bfv[2];
#pragma unroll
      for (int mi = 0; mi < 2; ++mi)
        af[mi] = *(const bf16x8*)&sY[(mi * 16 + (lane & 15)) * D_ + k0 + kk + (lane >> 4) * 8];
#pragma unroll
      for (int ni = 0; ni < 2; ++ni)
        bfv[ni] = *(const bf16x8*)&sB[(wave * 32 + ni * 16 + (lane & 15)) * BK + kk + (lane >> 4) * 8];
#pragma unroll
      for (int mi = 0; mi < 2; ++mi)
#pragma unroll
        for (int ni = 0; ni < 2; ++ni)
          acc[mi][ni] = __builtin_amdgcn_mfma_f32_16x16x32_bf16(af[mi], bfv[ni], acc[mi][ni], 0, 0, 0);
    }
    __syncthreads();
  }

  bf16_t* sC = sY;
#pragma unroll
  for (int mi = 0; mi < 2; ++mi) {
#pragma unroll
    for (int ni = 0; ni < 2; ++ni) {
      const int col  = wave * 32 + ni * 16 + (lane & 15);
      const int row0 = mi * 16 + ((lane >> 4) << 2);
      const float bv = bias[n0 + col];
#pragma unroll
      for (int r = 0; r < 4; ++r)
        sC[(row0 + r) * TN + col] = __float2bfloat16(acc[mi][ni][r] + bv);
    }
  }
  __syncthreads();
#pragma unroll
  for (int p = 0; p < (TM * TN) / 2048; ++p) {
    const int chunk = p * 256 + tid;
    const int rr = chunk / (TN / 8);
    const int cc = (chunk % (TN / 8)) * 8;
    *(uint4*)&O[(size_t)(m0 + rr) * D_ + n0 + cc] = *(const uint4*)&sC[rr * TN + cc];
  }
}

// Final head: h = X + P0..P3; logits[row, S-1, :] = h @ head_w + head_b.
__global__ void head_kernel(const float* __restrict__ X,
                            const bf16_t* __restrict__ P,
                            const float* __restrict__ hw,
                            const float* __restrict__ hb,
                            float* __restrict__ out, int t)
{
  const int row  = blockIdx.x * 4 + (threadIdx.x >> 6);
  const int lane = threadIdx.x & 63;
  const float* xr = X + (size_t)row * D_;
  const int c0 = lane * 8;
  float v[8];
  *(float4*)&v[0] = *(const float4*)&xr[c0];
  *(float4*)&v[4] = *(const float4*)&xr[c0 + 4];
#pragma unroll
  for (int z = 0; z < SPLITZ; ++z)
    fold_p(v, P + (size_t)z * B_ * D_ + (size_t)row * D_ + c0);
  float w[16];
#pragma unroll
  for (int i = 0; i < 4; ++i)
    *(float4*)&w[i * 4] = *(const float4*)&hw[lane * 16 + i * 4];
  float s0 = 0.f, s1 = 0.f;
#pragma unroll
  for (int i = 0; i < 8; ++i) { s0 += v[i] * w[2 * i]; s1 += v[i] * w[2 * i + 1]; }
#pragma unroll
  for (int o = 32; o; o >>= 1) { s0 += __shfl_xor(s0, o); s1 += __shfl_xor(s1, o); }
  if (lane == 0) {
    float* po = out + (size_t)row * (S_ * 2) + t * 2;
    po[0] = s0 + hb[0];
    po[1] = s1 + hb[1];
  }
}

// ---------------------------------------------------------------------------
// Prep kernels (run every launch; graph-safe)
// ---------------------------------------------------------------------------
__global__ void prep_wc(const float* __restrict__ qkv_w,
                        const float* __restrict__ out_w,
                        float* __restrict__ wc)
{
  const int n = blockIdx.x * 256 + threadIdx.x;
  const int k = blockIdx.y;
  const int l = blockIdx.z;
  const float* qrow = qkv_w + ((size_t)l * D_ + k) * (3 * D_) + 2 * D_;
  const float* ow   = out_w + (size_t)l * D_ * D_;
  float acc = 0.f;
  for (int j = 0; j < D_; ++j) acc += qrow[j] * ow[(size_t)j * D_ + n];
  wc[((size_t)l * D_ + k) * D_ + n] = acc;
}

__global__ void prep_bc(const float* __restrict__ qkv_b,
                        const float* __restrict__ out_w,
                        const float* __restrict__ out_b,
                        float* __restrict__ bc)
{
  const int l = blockIdx.x;
  const int n = threadIdx.x;
  const float* qb = qkv_b + (size_t)l * (3 * D_) + 2 * D_;
  const float* ow = out_w + (size_t)l * D_ * D_;
  float acc = out_b[(size_t)l * D_ + n];
  for (int j = 0; j < D_; ++j) acc += qb[j] * ow[(size_t)j * D_ + n];
  bc[(size_t)l * D_ + n] = acc;
}

// dst(C,R) bf16 = transpose(src(R,C) fp32), per-layer via blockIdx.z
__global__ void transpose_conv(const float* __restrict__ src,
                               bf16_t* __restrict__ dst, int R, int C)
{
  __shared__ float tile[32][33];
  const int l = blockIdx.z;
  const float* s = src + (size_t)l * R * C;
  bf16_t* d = dst + (size_t)l * R * C;
  const int c0 = blockIdx.x * 32, r0 = blockIdx.y * 32;
  const int tx = threadIdx.x, ty = threadIdx.y;
  tile[ty][tx] = s[(size_t)(r0 + ty) * C + (c0 + tx)];
  __syncthreads();
  d[(size_t)(c0 + ty) * R + (r0 + tx)] = __float2bfloat16(tile[tx][ty]);
}

// ---------------------------------------------------------------------------
extern "C" void kernel_launch(void* const* d_in, const int* in_sizes, int n_in,
                              void* d_out, int out_size, void* d_ws, size_t ws_size,
                              hipStream_t stream)
{
  const int*   a_seq     = (const int*)  d_in[0];
  const int*   b_seq     = (const int*)  d_in[1];
  const float* bit_emb   = (const float*)d_in[2];
  const float* start     = (const float*)d_in[3];
  const float* ln1_g     = (const float*)d_in[4];
  const float* ln1_b     = (const float*)d_in[5];
  const float* qkv_w     = (const float*)d_in[6];
  const float* qkv_b     = (const float*)d_in[7];
  const float* out_w     = (const float*)d_in[8];
  const float* out_b     = (const float*)d_in[9];
  const float* ln2_g     = (const float*)d_in[10];
  const float* ln2_b     = (const float*)d_in[11];
  const float* ff1_w     = (const float*)d_in[12];
  const float* ff1_b     = (const float*)d_in[13];
  const float* ff2_w     = (const float*)d_in[14];
  const float* ff2_b     = (const float*)d_in[15];
  const float* head_w    = (const float*)d_in[16];
  const float* head_b    = (const float*)d_in[17];
  float* out = (float*)d_out;

  // workspace layout
  char* ws = (char*)d_ws;
  float*  XA    = (float*) ws; ws += (size_t)B_ * D_ * 4;              // 8 MB
  float*  XB    = (float*) ws; ws += (size_t)B_ * D_ * 4;              // 8 MB
  bf16_t* Y     = (bf16_t*)ws; ws += (size_t)B_ * D_ * 2;              // 4 MB
  bf16_t* U     = (bf16_t*)ws; ws += (size_t)B_ * 4 * D_ * 2;          // 16 MB
  bf16_t* WCT   = (bf16_t*)ws; ws += (size_t)DEPTH_ * D_ * D_ * 2;     // 2 MB
  bf16_t* FF1T  = (bf16_t*)ws; ws += (size_t)DEPTH_ * D_ * 4 * D_ * 2; // 8 MB
  bf16_t* FF2T  = (bf16_t*)ws; ws += (size_t)DEPTH_ * 4 * D_ * D_ * 2; // 8 MB
  float*  BC    = (float*) ws; ws += (size_t)DEPTH_ * D_ * 4;          // 8 KB
  float*  WCTMP = (float*) ws; ws += (size_t)DEPTH_ * D_ * D_ * 4;     // 4 MB
  bf16_t* PSPL  = (bf16_t*)ws; ws += (size_t)SPLITZ * B_ * D_ * 2;     // 16 MB g3 split-K partials
  bf16_t* P1    = (bf16_t*)ws; ws += (size_t)B_ * D_ * 2;              // 4 MB g1 partial

  // ---- weight prep (per launch, identical every call) ----
  prep_wc<<<dim3(2, 512, 4), 256, 0, stream>>>(qkv_w, out_w, WCTMP);
  prep_bc<<<4, 512, 0, stream>>>(qkv_b, out_w, out_b, BC);
  transpose_conv<<<dim3(16, 16, 4),  dim3(32, 32), 0, stream>>>(WCTMP, WCT, 512, 512);
  transpose_conv<<<dim3(64, 16, 4),  dim3(32, 32), 0, stream>>>(ff1_w, FF1T, 512, 2048);
  transpose_conv<<<dim3(16, 64, 4),  dim3(32, 32), 0, stream>>>(ff2_w, FF2T, 2048, 512);

  // ---- recurrent steps ----
  // X ping-pong: addln XB->XA (l=0 residual base XA, ln_sum1 in-place),
  // lnfold l=1: XA->XB, l=2: XB->XA, l=3: XA->XB. Step ends on XB with
  // pending PSPL partials (folded by next addln / final head).
  for (int t = 0; t < S_; ++t) {
    if (t == 0)
      addln_gemm<<<dim3(B_ / 32, 4), 256, 0, stream>>>(
          a_seq, b_seq, bit_emb, start, 0, nullptr, XA,
          ln1_g, ln1_b, WCT, BC, P1, t, head_w, head_b, nullptr);
    else
      addln_gemm<<<dim3(B_ / 32, 4), 256, 0, stream>>>(
          a_seq, b_seq, bit_emb, XB, D_, PSPL, XA,
          ln1_g, ln1_b, WCT, BC, P1, t, head_w, head_b, out);
    float* cur = XA;
    float* alt = XB;
    for (int l = 0; l < DEPTH_; ++l) {
      if (l > 0) {
        // x = cur + fold(PSPL) -> alt ; y = LN1[l](x) ; P1 = y@Wc[l]+bc[l]
        lnfold_gemm<<<dim3(B_ / 32, 4), 256, 0, stream>>>(
            cur, PSPL, alt,
            ln1_g + (size_t)l * D_, ln1_b + (size_t)l * D_,
            WCT + (size_t)l * D_ * D_, BC + (size_t)l * D_, P1);
        float* tmp = cur; cur = alt; alt = tmp;
      }
      // x += P1 (in-place on cur) ; y = LN2[l](x)
      ln_sum1_kernel<<<B_ / 4, 256, 0, stream>>>(cur, P1,
                                                 ln2_g + (size_t)l * D_,
                                                 ln2_b + (size_t)l * D_, Y);
      // u = relu(y @ ff1[l] + b1)  (128x128, BK=64, 512 blocks)
      gemm_bf16<128, 128, 1, 1><<<dim3(32, 16), 256, 0, stream>>>(
          Y, FF1T + (size_t)l * D_ * 4 * D_, ff1_b + (size_t)l * 4 * D_, U,
          B_, 4 * D_, D_);
      // PSPL[z] = bf16(u @ ff2[l] (+b2 in z=0))  (128x128, split-K=4,
      //           grid (32,4,4)=512 blocks, 8 BK-iters/block)
      gemm_bf16<128, 128, 2, SPLITZ><<<dim3(32, 4, SPLITZ), 256, 0, stream>>>(
          U, FF2T + (size_t)l * 4 * D_ * D_, ff2_b + (size_t)l * D_, PSPL,
          B_, D_, 4 * D_);
      // partials folded by next lnfold / addln / head
    }
    // invariant: cur == XB here (addln wrote XA; 3 lnfold swaps -> XB)
  }
  head_kernel<<<B_ / 4, 256, 0, stream>>>(XB, PSPL, head_w, head_b, out, S_ - 1);
}

// Round 4
// 14751.524 us; speedup vs baseline: 1.2496x; 1.0094x over previous
//
#include <hip/hip_runtime.h>
#include <hip/hip_bf16.h>
#include <stdint.h>
#include <stddef.h>

// Problem constants
#define B_ 4096
#define S_ 64
#define D_ 512
#define DEPTH_ 4

// ---------------------------------------------------------------------------
// R14 design = R13 (best known, 14889us) + one co-designed delta pair in the
// small D x D GEMMs (addln_gemm / lnfold_gemm):
//  * B operand read DIRECT from global (Wc panel = 0.5MB, L2-resident;
//    lane groups {l,l+16,l+32,l+48} form contiguous 64B per B-row). This
//    removes sB staging AND all 16 per-iter barriers: A-panel (sY) is
//    written once in the prologue, so the K-loop is a barrier-free
//    {global_load + ds_read + MFMA} stream the compiler can pipeline.
//  * sY XOR-swizzle (T2): with barriers gone the sY ds_read_b128 is on the
//    critical path, and row-stride 1024B => lanes 0-15 same-bank (16-way).
//    elem ^= (row&7)<<3 on store+read makes it 2-way (free). Values are
//    bit-identical -> absmax unchanged.
//  * LDS per block drops 48KB -> 32KB (more co-residency).
//  * Big GEMMs (g2/g3) untouched: 2-phase barrier-dominated regime, T2 and
//    direct-B don't apply (regime gate); B panels too big for L2-direct.
//  * Locked per R10-R13: m97 2-barrier K-loop for big GEMMs, BK=64,
//    global_load_lds width=16, coalesced LDS-staged epilogues, grids >=512
//    blocks, split-K=4 g3 with plain bf16 partials, no cross-block sync,
//    no XCD swizzle.
// ---------------------------------------------------------------------------

typedef __attribute__((ext_vector_type(8))) __bf16 bf16x8;
typedef __attribute__((ext_vector_type(4))) float f32x4;
typedef __hip_bfloat16 bf16_t;

constexpr int SPLITZ = 4;   // g3 split-K partials

__device__ __forceinline__ void async_copy16(const void* g, void* lds) {
  __builtin_amdgcn_global_load_lds(
      (const __attribute__((address_space(1))) void*)g,
      (__attribute__((address_space(3))) void*)lds, 16, 0, 0);
}

__device__ __forceinline__ float bf2f(bf16_t h) { return __bfloat162float(h); }

// fold bf16 partial row-chunk into v[8]
__device__ __forceinline__ void fold_p(float v[8], const bf16_t* pz)
{
  alignas(16) bf16_t t[8];
  *(uint4*)t = *(const uint4*)pz;
#pragma unroll
  for (int i = 0; i < 8; ++i) v[i] += bf2f(t[i]);
}

// LayerNorm row math shared by the storers
__device__ __forceinline__ void ln_vals(const float v[8],
                                        const float* __restrict__ gamma,
                                        const float* __restrict__ beta,
                                        int lane, bf16_t o8[8])
{
  float s = 0.f, ss = 0.f;
#pragma unroll
  for (int i = 0; i < 8; ++i) { s += v[i]; ss += v[i] * v[i]; }
#pragma unroll
  for (int o = 32; o; o >>= 1) { s += __shfl_xor(s, o); ss += __shfl_xor(ss, o); }
  const float m   = s * (1.f / D_);
  const float inv = rsqrtf(ss * (1.f / D_) - m * m + 1e-5f);
  const int c0 = lane * 8;
  float g[8], b[8];
  *(float4*)&g[0] = *(const float4*)&gamma[c0];
  *(float4*)&g[4] = *(const float4*)&gamma[c0 + 4];
  *(float4*)&b[0] = *(const float4*)&beta[c0];
  *(float4*)&b[4] = *(const float4*)&beta[c0 + 4];
#pragma unroll
  for (int i = 0; i < 8; ++i)
    o8[i] = __float2bfloat16((v[i] - m) * inv * g[i] + b[i]);
}

// LN + plain row store (global Y rows)
__device__ __forceinline__ void ln_store(const float v[8],
                                         const float* __restrict__ gamma,
                                         const float* __restrict__ beta,
                                         bf16_t* yrow, int lane)
{
  alignas(16) bf16_t o8[8];
  ln_vals(v, gamma, beta, lane, o8);
  *(uint4*)&yrow[lane * 8] = *(const uint4*)o8;
}

// LN + XOR-swizzled LDS row store: elem ^= (row&7)<<3 (bank-spread for the
// stride-1024B ds_read_b128 in the K-loop; bijective within the row)
__device__ __forceinline__ void ln_store_swz(const float v[8],
                                             const float* __restrict__ gamma,
                                             const float* __restrict__ beta,
                                             bf16_t* srow, int row, int lane)
{
  alignas(16) bf16_t o8[8];
  ln_vals(v, gamma, beta, lane, o8);
  const int c0s = (lane * 8) ^ ((row & 7) << 3);
  *(uint4*)&srow[c0s] = *(const uint4*)o8;
}

// ---------------------------------------------------------------------------
// GEMM: C(M,N) = A(M,K) @ Bt(N,K)^T  (+bias)
//   EPI 1: O[row*N+col]  = bf16(relu(acc+b))   (SPLITK==1)
//   EPI 2: O[z*M*N + row*N+col] = bf16(acc (+bias if z==0))
// ---------------------------------------------------------------------------
template<int TM, int TN, int EPI, int SPLITK>
__launch_bounds__(256)
__global__ void gemm_bf16(const bf16_t* __restrict__ A,
                          const bf16_t* __restrict__ Bt,
                          const float* __restrict__ bias,
                          bf16_t* __restrict__ O,
                          int M, int N, int K)
{
  constexpr int BK  = 64;
  constexpr int WM  = TM / 2, WN = TN / 2;
  constexpr int NMI = WM / 16, NNI = WN / 16;
  constexpr int CA  = TM / 8, CB = TN / 8;   // 1KB chunks (8 rows of 128B)
  static_assert(TM * TN <= (TM + TN) * BK, "C tile must fit in staging LDS");

  __shared__ __align__(16) bf16_t smem[(TM + TN) * BK];
  bf16_t* sA = smem;
  bf16_t* sB = smem + TM * BK;

  const int tid  = threadIdx.x;
  const int lane = tid & 63;
  const int wave = tid >> 6;
  const int wm   = wave & 1;
  const int wn   = wave >> 1;
  const int m0   = blockIdx.x * TM;
  const int n0   = blockIdx.y * TN;
  const int KS   = K / SPLITK;
  const int kbeg = blockIdx.z * KS;

  const int lr = lane >> 3;        // row within 1KB chunk (8 rows)
  const int lc = (lane & 7) * 8;   // bf16 col within row

  f32x4 acc[NMI][NNI];
#pragma unroll
  for (int mi = 0; mi < NMI; ++mi)
#pragma unroll
    for (int ni = 0; ni < NNI; ++ni)
      acc[mi][ni] = (f32x4){0.f, 0.f, 0.f, 0.f};

  for (int k0 = kbeg; k0 < kbeg + KS; k0 += BK) {
#pragma unroll
    for (int c = wave; c < CA; c += 4) {
      const bf16_t* g = A + (size_t)(m0 + c * 8 + lr) * K + (k0 + lc);
      async_copy16(g, (char*)sA + c * 1024);
    }
#pragma unroll
    for (int c = wave; c < CB; c += 4) {
      const bf16_t* g = Bt + (size_t)(n0 + c * 8 + lr) * K + (k0 + lc);
      async_copy16(g, (char*)sB + c * 1024);
    }
    __syncthreads();   // drains vmcnt(0) -> LDS ready

#pragma unroll
    for (int kk = 0; kk < BK; kk += 32) {
      bf16x8 af[NMI], bfv[NNI];
#pragma unroll
      for (int mi = 0; mi < NMI; ++mi)
        af[mi] = *(const bf16x8*)&sA[(wm * WM + mi * 16 + (lane & 15)) * BK + kk + (lane >> 4) * 8];
#pragma unroll
      for (int ni = 0; ni < NNI; ++ni)
        bfv[ni] = *(const bf16x8*)&sB[(wn * WN + ni * 16 + (lane & 15)) * BK + kk + (lane >> 4) * 8];
#pragma unroll
      for (int mi = 0; mi < NMI; ++mi)
#pragma unroll
        for (int ni = 0; ni < NNI; ++ni)
          acc[mi][ni] = __builtin_amdgcn_mfma_f32_16x16x32_bf16(af[mi], bfv[ni], acc[mi][ni], 0, 0, 0);
    }
    __syncthreads();   // protect LDS before next stage / before sC reuse
  }

  // Coalesced epilogue: round into LDS (reuse staging buffer), then
  // row-major uint4 stores. C/D layout (m89/m91): col=lane&15,
  // row=(lane>>4)*4 + r.
  bf16_t* sC = smem;
#pragma unroll
  for (int mi = 0; mi < NMI; ++mi) {
#pragma unroll
    for (int ni = 0; ni < NNI; ++ni) {
      const int col  = wn * WN + ni * 16 + (lane & 15);
      const int row0 = wm * WM + mi * 16 + ((lane >> 4) << 2);
      const float bv = (SPLITK == 1 || blockIdx.z == 0) ? bias[n0 + col] : 0.f;
#pragma unroll
      for (int r = 0; r < 4; ++r) {
        float v = acc[mi][ni][r] + bv;
        if constexpr (EPI == 1) v = v > 0.f ? v : 0.f;
        sC[(row0 + r) * TN + col] = __float2bfloat16(v);
      }
    }
  }
  __syncthreads();
  bf16_t* Ob = O + (EPI == 2 ? (size_t)blockIdx.z * M * N : (size_t)0);
#pragma unroll
  for (int p = 0; p < (TM * TN) / 2048; ++p) {
    const int chunk = p * 256 + tid;
    const int rr = chunk / (TN / 8);
    const int cc = (chunk % (TN / 8)) * 8;
    *(uint4*)&Ob[(size_t)(m0 + rr) * N + n0 + cc] = *(const uint4*)&sC[rr * TN + cc];
  }
}

// x = X + P1 (bf16 partial); write X; y = LN(x). 4 rows/block.
__global__ void ln_sum1_kernel(float* __restrict__ X,
                               const bf16_t* __restrict__ P,
                               const float* __restrict__ gamma,
                               const float* __restrict__ beta,
                               bf16_t* __restrict__ Y)
{
  const int row  = blockIdx.x * 4 + (threadIdx.x >> 6);
  const int lane = threadIdx.x & 63;
  const int c0 = lane * 8;
  float* xr = X + (size_t)row * D_;
  float v[8];
  *(float4*)&v[0] = *(const float4*)&xr[c0];
  *(float4*)&v[4] = *(const float4*)&xr[c0 + 4];
  fold_p(v, P + (size_t)row * D_ + c0);
  *(float4*)&xr[c0]     = *(const float4*)&v[0];
  *(float4*)&xr[c0 + 4] = *(const float4*)&v[4];
  ln_store(v, gamma, beta, Y + (size_t)row * D_, lane);
}

// ---------------------------------------------------------------------------
// Barrier-free K-loop for the small D x D GEMM (shared by lnfold/addln):
// A = swizzled sY (LDS, written once), B = direct global (L2-hot Wc panel).
// Bit-identical operand values to the staged version.
// ---------------------------------------------------------------------------
__device__ __forceinline__ void small_gemm_loop(const bf16_t* __restrict__ sY,
                                                const bf16_t* __restrict__ Bt,
                                                int n0, int wave, int lane,
                                                f32x4 acc[2][2])
{
  const bf16_t* b0 = Bt + (size_t)(n0 + wave * 32 + (lane & 15)) * D_ + (lane >> 4) * 8;
  const bf16_t* b1 = b0 + (size_t)16 * D_;
  const int r0 = (lane & 15);
  const int r1 = 16 + (lane & 15);
  const int x0 = (r0 & 7) << 3;          // swizzle XOR for rows 0-15
  const int ka = (lane >> 4) * 8;
#pragma unroll
  for (int k0 = 0; k0 < D_; k0 += 32) {
    bf16x8 af0, af1, bv0, bv1;
    bv0 = *(const bf16x8*)&b0[k0];
    bv1 = *(const bf16x8*)&b1[k0];
    af0 = *(const bf16x8*)&sY[r0 * D_ + ((k0 + ka) ^ x0)];
    af1 = *(const bf16x8*)&sY[r1 * D_ + ((k0 + ka) ^ x0)];  // (r1&7)==(r0&7)
    acc[0][0] = __builtin_amdgcn_mfma_f32_16x16x32_bf16(af0, bv0, acc[0][0], 0, 0, 0);
    acc[0][1] = __builtin_amdgcn_mfma_f32_16x16x32_bf16(af0, bv1, acc[0][1], 0, 0, 0);
    acc[1][0] = __builtin_amdgcn_mfma_f32_16x16x32_bf16(af1, bv0, acc[1][0], 0, 0, 0);
    acc[1][1] = __builtin_amdgcn_mfma_f32_16x16x32_bf16(af1, bv1, acc[1][1], 0, 0, 0);
  }
}

// shared coalesced epilogue through sC (=sY reused) for the small GEMMs
__device__ __forceinline__ void small_gemm_epi(bf16_t* sC, bf16_t* __restrict__ O,
                                               const float* __restrict__ bias,
                                               const f32x4 acc[2][2],
                                               int m0, int n0, int wave, int lane,
                                               int tid)
{
  constexpr int TM = 32, TN = 128;
#pragma unroll
  for (int mi = 0; mi < 2; ++mi) {
#pragma unroll
    for (int ni = 0; ni < 2; ++ni) {
      const int col  = wave * 32 + ni * 16 + (lane & 15);
      const int row0 = mi * 16 + ((lane >> 4) << 2);
      const float bv = bias[n0 + col];
#pragma unroll
      for (int r = 0; r < 4; ++r)
        sC[(row0 + r) * TN + col] = __float2bfloat16(acc[mi][ni][r] + bv);
    }
  }
  __syncthreads();
#pragma unroll
  for (int p = 0; p < (TM * TN) / 2048; ++p) {   // 2 passes
    const int chunk = p * 256 + tid;
    const int rr = chunk / (TN / 8);
    const int cc = (chunk % (TN / 8)) * 8;
    *(uint4*)&O[(size_t)(m0 + rr) * D_ + n0 + cc] = *(const uint4*)&sC[rr * TN + cc];
  }
}

// ---------------------------------------------------------------------------
// Fused [x = Xin + sum_{z<4} PSPL; LN1; P1 = y@Wc + bc], layers 1..3.
// TM=32 rows, TN=128 cols; grid (B/32, 4) = 512 blocks, 256 thr.
// LDS: sY 32KB only. Two barriers total (post-prologue, pre-epilogue).
// blockIdx.y==0 writes Xout (ping-pong buffer, no race with Xin reads).
// ---------------------------------------------------------------------------
__launch_bounds__(256)
__global__ void lnfold_gemm(const float* __restrict__ Xin,
                            const bf16_t* __restrict__ P,
                            float* __restrict__ Xout,
                            const float* __restrict__ gamma,
                            const float* __restrict__ beta,
                            const bf16_t* __restrict__ Bt,   // WCT layer slice
                            const float* __restrict__ bias,  // BC layer slice
                            bf16_t* __restrict__ O)          // P1
{
  constexpr int TM = 32;
  __shared__ __align__(16) bf16_t sY[TM * D_];   // 32KB

  const int tid  = threadIdx.x;
  const int lane = tid & 63;
  const int wave = tid >> 6;
  const int m0   = blockIdx.x * TM;
  const int n0   = blockIdx.y * 128;
  const int c0   = lane * 8;

  // ---- prologue: fold partials + LN (swizzled store), 8 rows per wave ----
#pragma unroll
  for (int i = 0; i < 8; ++i) {
    const int row  = wave * 8 + i;
    const int grow = m0 + row;
    const float* xr = Xin + (size_t)grow * D_ + c0;
    float v[8];
    *(float4*)&v[0] = *(const float4*)&xr[0];
    *(float4*)&v[4] = *(const float4*)&xr[4];
#pragma unroll
    for (int z = 0; z < SPLITZ; ++z)
      fold_p(v, P + (size_t)z * B_ * D_ + (size_t)grow * D_ + c0);
    if (blockIdx.y == 0) {
      float* xo = Xout + (size_t)grow * D_ + c0;
      *(float4*)&xo[0] = *(const float4*)&v[0];
      *(float4*)&xo[4] = *(const float4*)&v[4];
    }
    ln_store_swz(v, gamma, beta, &sY[row * D_], row, lane);
  }
  __syncthreads();   // sY visible to all waves

  f32x4 acc[2][2];
#pragma unroll
  for (int mi = 0; mi < 2; ++mi)
#pragma unroll
    for (int ni = 0; ni < 2; ++ni)
      acc[mi][ni] = (f32x4){0.f, 0.f, 0.f, 0.f};

  small_gemm_loop(sY, Bt, n0, wave, lane, acc);

  __syncthreads();   // all sY reads done before reuse as sC
  small_gemm_epi(sY, O, bias, acc, m0, n0, wave, lane, tid);
}

// ---------------------------------------------------------------------------
// Fused step boundary + g1 (layer 0):
//  h = hsrc (+ fold PSPL if P); head(t-1) from h (if out, blockIdx.y==0);
//  x = emb_a + emb_b + h -> Xout (y==0); y = LN1_0(x) -> sY (swizzled);
//  P1 = y @ Wc0 + bc0.  Same geometry as lnfold_gemm.
// ---------------------------------------------------------------------------
__launch_bounds__(256)
__global__ void addln_gemm(const int* __restrict__ a_seq,
                           const int* __restrict__ b_seq,
                           const float* __restrict__ bit_emb,
                           const float* __restrict__ hsrc, int hstride,
                           const bf16_t* __restrict__ P,
                           float* __restrict__ Xout,
                           const float* __restrict__ gamma,
                           const float* __restrict__ beta,
                           const bf16_t* __restrict__ Bt,   // WCT layer 0
                           const float* __restrict__ bias,  // BC layer 0
                           bf16_t* __restrict__ O,          // P1
                           int t,
                           const float* __restrict__ hw,
                           const float* __restrict__ hb,
                           float* __restrict__ out)
{
  constexpr int TM = 32;
  __shared__ __align__(16) bf16_t sY[TM * D_];   // 32KB

  const int tid  = threadIdx.x;
  const int lane = tid & 63;
  const int wave = tid >> 6;
  const int m0   = blockIdx.x * TM;
  const int n0   = blockIdx.y * 128;
  const int c0   = lane * 8;

  const bool do_head = (out != nullptr) && (blockIdx.y == 0);
  float w[16];
  if (do_head) {
#pragma unroll
    for (int i = 0; i < 4; ++i)
      *(float4*)&w[i * 4] = *(const float4*)&hw[lane * 16 + i * 4];
  }

#pragma unroll
  for (int i = 0; i < 8; ++i) {
    const int row  = wave * 8 + i;
    const int grow = m0 + row;
    const int ai = a_seq[grow * S_ + t];
    const int bi = b_seq[grow * S_ + t];
    const float* pr = hsrc + (size_t)grow * hstride + c0;
    float p[8];
    *(float4*)&p[0] = *(const float4*)&pr[0];
    *(float4*)&p[4] = *(const float4*)&pr[4];
    if (P != nullptr) {
#pragma unroll
      for (int z = 0; z < SPLITZ; ++z)
        fold_p(p, P + (size_t)z * B_ * D_ + (size_t)grow * D_ + c0);
    }
    if (do_head) {
      float s0 = 0.f, s1 = 0.f;
#pragma unroll
      for (int j = 0; j < 8; ++j) { s0 += p[j] * w[2 * j]; s1 += p[j] * w[2 * j + 1]; }
#pragma unroll
      for (int o = 32; o; o >>= 1) { s0 += __shfl_xor(s0, o); s1 += __shfl_xor(s1, o); }
      if (lane == 0) {
        float* po = out + (size_t)grow * (S_ * 2) + (t - 1) * 2;
        po[0] = s0 + hb[0];
        po[1] = s1 + hb[1];
      }
    }
    float ea[8], eb[8], v[8];
    *(float4*)&ea[0] = *(const float4*)&bit_emb[ai * D_ + c0];
    *(float4*)&ea[4] = *(const float4*)&bit_emb[ai * D_ + c0 + 4];
    *(float4*)&eb[0] = *(const float4*)&bit_emb[bi * D_ + c0];
    *(float4*)&eb[4] = *(const float4*)&bit_emb[bi * D_ + c0 + 4];
#pragma unroll
    for (int j = 0; j < 8; ++j) v[j] = ea[j] + eb[j] + p[j];
    if (blockIdx.y == 0) {
      float* xo = Xout + (size_t)grow * D_ + c0;
      *(float4*)&xo[0] = *(const float4*)&v[0];
      *(float4*)&xo[4] = *(const float4*)&v[4];
    }
    ln_store_swz(v, gamma, beta, &sY[row * D_], row, lane);
  }
  __syncthreads();   // sY visible

  f32x4 acc[2][2];
#pragma unroll
  for (int mi = 0; mi < 2; ++mi)
#pragma unroll
    for (int ni = 0; ni < 2; ++ni)
      acc[mi][ni] = (f32x4){0.f, 0.f, 0.f, 0.f};

  small_gemm_loop(sY, Bt, n0, wave, lane, acc);

  __syncthreads();
  small_gemm_epi(sY, O, bias, acc, m0, n0, wave, lane, tid);
}

// Final head: h = X + P0..P3; logits[row, S-1, :] = h @ head_w + head_b.
__global__ void head_kernel(const float* __restrict__ X,
                            const bf16_t* __restrict__ P,
                            const float* __restrict__ hw,
                            const float* __restrict__ hb,
                            float* __restrict__ out, int t)
{
  const int row  = blockIdx.x * 4 + (threadIdx.x >> 6);
  const int lane = threadIdx.x & 63;
  const float* xr = X + (size_t)row * D_;
  const int c0 = lane * 8;
  float v[8];
  *(float4*)&v[0] = *(const float4*)&xr[c0];
  *(float4*)&v[4] = *(const float4*)&xr[c0 + 4];
#pragma unroll
  for (int z = 0; z < SPLITZ; ++z)
    fold_p(v, P + (size_t)z * B_ * D_ + (size_t)row * D_ + c0);
  float w[16];
#pragma unroll
  for (int i = 0; i < 4; ++i)
    *(float4*)&w[i * 4] = *(const float4*)&hw[lane * 16 + i * 4];
  float s0 = 0.f, s1 = 0.f;
#pragma unroll
  for (int i = 0; i < 8; ++i) { s0 += v[i] * w[2 * i]; s1 += v[i] * w[2 * i + 1]; }
#pragma unroll
  for (int o = 32; o; o >>= 1) { s0 += __shfl_xor(s0, o); s1 += __shfl_xor(s1, o); }
  if (lane == 0) {
    float* po = out + (size_t)row * (S_ * 2) + t * 2;
    po[0] = s0 + hb[0];
    po[1] = s1 + hb[1];
  }
}

// ---------------------------------------------------------------------------
// Prep kernels (run every launch; graph-safe)
// ---------------------------------------------------------------------------
__global__ void prep_wc(const float* __restrict__ qkv_w,
                        const float* __restrict__ out_w,
                        float* __restrict__ wc)
{
  const int n = blockIdx.x * 256 + threadIdx.x;
  const int k = blockIdx.y;
  const int l = blockIdx.z;
  const float* qrow = qkv_w + ((size_t)l * D_ + k) * (3 * D_) + 2 * D_;
  const float* ow   = out_w + (size_t)l * D_ * D_;
  float acc = 0.f;
  for (int j = 0; j < D_; ++j) acc += qrow[j] * ow[(size_t)j * D_ + n];
  wc[((size_t)l * D_ + k) * D_ + n] = acc;
}

__global__ void prep_bc(const float* __restrict__ qkv_b,
                        const float* __restrict__ out_w,
                        const float* __restrict__ out_b,
                        float* __restrict__ bc)
{
  const int l = blockIdx.x;
  const int n = threadIdx.x;
  const float* qb = qkv_b + (size_t)l * (3 * D_) + 2 * D_;
  const float* ow = out_w + (size_t)l * D_ * D_;
  float acc = out_b[(size_t)l * D_ + n];
  for (int j = 0; j < D_; ++j) acc += qb[j] * ow[(size_t)j * D_ + n];
  bc[(size_t)l * D_ + n] = acc;
}

// dst(C,R) bf16 = transpose(src(R,C) fp32), per-layer via blockIdx.z
__global__ void transpose_conv(const float* __restrict__ src,
                               bf16_t* __restrict__ dst, int R, int C)
{
  __shared__ float tile[32][33];
  const int l = blockIdx.z;
  const float* s = src + (size_t)l * R * C;
  bf16_t* d = dst + (size_t)l * R * C;
  const int c0 = blockIdx.x * 32, r0 = blockIdx.y * 32;
  const int tx = threadIdx.x, ty = threadIdx.y;
  tile[ty][tx] = s[(size_t)(r0 + ty) * C + (c0 + tx)];
  __syncthreads();
  d[(size_t)(c0 + ty) * R + (r0 + tx)] = __float2bfloat16(tile[tx][ty]);
}

// ---------------------------------------------------------------------------
extern "C" void kernel_launch(void* const* d_in, const int* in_sizes, int n_in,
                              void* d_out, int out_size, void* d_ws, size_t ws_size,
                              hipStream_t stream)
{
  const int*   a_seq     = (const int*)  d_in[0];
  const int*   b_seq     = (const int*)  d_in[1];
  const float* bit_emb   = (const float*)d_in[2];
  const float* start     = (const float*)d_in[3];
  const float* ln1_g     = (const float*)d_in[4];
  const float* ln1_b     = (const float*)d_in[5];
  const float* qkv_w     = (const float*)d_in[6];
  const float* qkv_b     = (const float*)d_in[7];
  const float* out_w     = (const float*)d_in[8];
  const float* out_b     = (const float*)d_in[9];
  const float* ln2_g     = (const float*)d_in[10];
  const float* ln2_b     = (const float*)d_in[11];
  const float* ff1_w     = (const float*)d_in[12];
  const float* ff1_b     = (const float*)d_in[13];
  const float* ff2_w     = (const float*)d_in[14];
  const float* ff2_b     = (const float*)d_in[15];
  const float* head_w    = (const float*)d_in[16];
  const float* head_b    = (const float*)d_in[17];
  float* out = (float*)d_out;

  // workspace layout
  char* ws = (char*)d_ws;
  float*  XA    = (float*) ws; ws += (size_t)B_ * D_ * 4;              // 8 MB
  float*  XB    = (float*) ws; ws += (size_t)B_ * D_ * 4;              // 8 MB
  bf16_t* Y     = (bf16_t*)ws; ws += (size_t)B_ * D_ * 2;              // 4 MB
  bf16_t* U     = (bf16_t*)ws; ws += (size_t)B_ * 4 * D_ * 2;          // 16 MB
  bf16_t* WCT   = (bf16_t*)ws; ws += (size_t)DEPTH_ * D_ * D_ * 2;     // 2 MB
  bf16_t* FF1T  = (bf16_t*)ws; ws += (size_t)DEPTH_ * D_ * 4 * D_ * 2; // 8 MB
  bf16_t* FF2T  = (bf16_t*)ws; ws += (size_t)DEPTH_ * 4 * D_ * D_ * 2; // 8 MB
  float*  BC    = (float*) ws; ws += (size_t)DEPTH_ * D_ * 4;          // 8 KB
  float*  WCTMP = (float*) ws; ws += (size_t)DEPTH_ * D_ * D_ * 4;     // 4 MB
  bf16_t* PSPL  = (bf16_t*)ws; ws += (size_t)SPLITZ * B_ * D_ * 2;     // 16 MB g3 split-K partials
  bf16_t* P1    = (bf16_t*)ws; ws += (size_t)B_ * D_ * 2;              // 4 MB g1 partial

  // ---- weight prep (per launch, identical every call) ----
  prep_wc<<<dim3(2, 512, 4), 256, 0, stream>>>(qkv_w, out_w, WCTMP);
  prep_bc<<<4, 512, 0, stream>>>(qkv_b, out_w, out_b, BC);
  transpose_conv<<<dim3(16, 16, 4),  dim3(32, 32), 0, stream>>>(WCTMP, WCT, 512, 512);
  transpose_conv<<<dim3(64, 16, 4),  dim3(32, 32), 0, stream>>>(ff1_w, FF1T, 512, 2048);
  transpose_conv<<<dim3(16, 64, 4),  dim3(32, 32), 0, stream>>>(ff2_w, FF2T, 2048, 512);

  // ---- recurrent steps ----
  // X ping-pong: addln XB->XA (l=0 residual base XA, ln_sum1 in-place),
  // lnfold l=1: XA->XB, l=2: XB->XA, l=3: XA->XB. Step ends on XB with
  // pending PSPL partials (folded by next addln / final head).
  for (int t = 0; t < S_; ++t) {
    if (t == 0)
      addln_gemm<<<dim3(B_ / 32, 4), 256, 0, stream>>>(
          a_seq, b_seq, bit_emb, start, 0, nullptr, XA,
          ln1_g, ln1_b, WCT, BC, P1, t, head_w, head_b, nullptr);
    else
      addln_gemm<<<dim3(B_ / 32, 4), 256, 0, stream>>>(
          a_seq, b_seq, bit_emb, XB, D_, PSPL, XA,
          ln1_g, ln1_b, WCT, BC, P1, t, head_w, head_b, out);
    float* cur = XA;
    float* alt = XB;
    for (int l = 0; l < DEPTH_; ++l) {
      if (l > 0) {
        // x = cur + fold(PSPL) -> alt ; y = LN1[l](x) ; P1 = y@Wc[l]+bc[l]
        lnfold_gemm<<<dim3(B_ / 32, 4), 256, 0, stream>>>(
            cur, PSPL, alt,
            ln1_g + (size_t)l * D_, ln1_b + (size_t)l * D_,
            WCT + (size_t)l * D_ * D_, BC + (size_t)l * D_, P1);
        float* tmp = cur; cur = alt; alt = tmp;
      }
      // x += P1 (in-place on cur) ; y = LN2[l](x)
      ln_sum1_kernel<<<B_ / 4, 256, 0, stream>>>(cur, P1,
                                                 ln2_g + (size_t)l * D_,
                                                 ln2_b + (size_t)l * D_, Y);
      // u = relu(y @ ff1[l] + b1)  (128x128, BK=64, 512 blocks)
      gemm_bf16<128, 128, 1, 1><<<dim3(32, 16), 256, 0, stream>>>(
          Y, FF1T + (size_t)l * D_ * 4 * D_, ff1_b + (size_t)l * 4 * D_, U,
          B_, 4 * D_, D_);
      // PSPL[z] = bf16(u @ ff2[l] (+b2 in z=0))  (128x128, split-K=4,
      //           grid (32,4,4)=512 blocks, 8 BK-iters/block)
      gemm_bf16<128, 128, 2, SPLITZ><<<dim3(32, 4, SPLITZ), 256, 0, stream>>>(
          U, FF2T + (size_t)l * 4 * D_ * D_, ff2_b + (size_t)l * D_, PSPL,
          B_, D_, 4 * D_);
      // partials folded by next lnfold / addln / head
    }
    // invariant: cur == XB here (addln wrote XA; 3 lnfold swaps -> XB)
  }
  head_kernel<<<B_ / 4, 256, 0, stream>>>(XB, PSPL, head_w, head_b, out, S_ - 1);
}